// Round 16
// baseline (233.380 us; speedup 1.0000x reference)
//
#include <hip/hip_runtime.h>
#include <math.h>
#include <float.h>

#define BN_EPS 1e-5f
#define PBLK   8192      // edges per partition block
#define NBUCKP 1664      // padded bucket count (scan width; N <= 106496)
#define ACAP   2048      // arena ints per 64-node bucket
#define STCAP  1536      // LDS stage capacity (expected bucket max ~1190)

typedef short s16x8 __attribute__((ext_vector_type(8)));
typedef float f32x4 __attribute__((ext_vector_type(4)));

__device__ __forceinline__ unsigned short f2bf(float f) {
    unsigned u = __float_as_uint(f);
    u += 0x7FFFu + ((u >> 16) & 1u);          // round-to-nearest-even
    return (unsigned short)(u >> 16);
}
__device__ __forceinline__ float bf2f(unsigned short b) {
    return __uint_as_float(((unsigned)b) << 16);
}

// ---------------------------------------------------------------------------
// Kernel A: prep + partition (1024 blocks share xb conversion; blocks < EB
// partition edges into per-bucket arenas; bucket = dst>>6).
// val = (dst&63)<<17 | src  (requires N < 131072).
// ---------------------------------------------------------------------------
__global__ __launch_bounds__(512) void prep_partition(
    const float* __restrict__ x, unsigned short* __restrict__ xb,
    const float* __restrict__ W1, const float* __restrict__ W2,
    unsigned short* __restrict__ w1t, unsigned short* __restrict__ w2t,
    const int* __restrict__ src, const int* __restrict__ dst,
    int* __restrict__ bcur0, int* __restrict__ packed2,
    int N, int E, int EB)
{
    __shared__ int hist[NBUCKP], lstart[NBUCKP], goff[NBUCKP], cur[NBUCKP];
    __shared__ int sorted[PBLK];
    __shared__ unsigned short sbkt[PBLK];

    int tid = threadIdx.x;
    int lane = tid & 63;
    int blk = blockIdx.x;

    // --- xb conversion (grid-strided over ALL blocks) ---
    int n4 = N * 16;
    for (int i = blk * 512 + tid; i < n4; i += gridDim.x * 512) {
        float4 f = *(const float4*)(x + (size_t)i * 4);
        ushort4 o;
        o.x = f2bf(f.x); o.y = f2bf(f.y); o.z = f2bf(f.z); o.w = f2bf(f.w);
        *(ushort4*)(xb + (size_t)i * 4) = o;
    }
    if (blk == 0)
        for (int idx = tid; idx < 4096; idx += 512)
            w1t[idx] = f2bf(W1[(idx & 63) * 64 + (idx >> 6)]);
    if (blk == 1)
        for (int idx = tid; idx < 4096; idx += 512)
            w2t[idx] = f2bf(W2[(idx & 63) * 64 + (idx >> 6)]);

    if (blk >= EB) return;

    // --- edge partition (blocks < EB only) ---
    int e0 = blk * PBLK;
    int cnt = E - e0; if (cnt > PBLK) cnt = PBLK; if (cnt < 0) cnt = 0;

    for (int i = tid; i < NBUCKP; i += 512) hist[i] = 0;
    __syncthreads();
    for (int i = tid; i < cnt; i += 512)
        atomicAdd(&hist[dst[e0 + i] >> 6], 1);
    __syncthreads();
    if (tid < 64) {
        int carry = 0;
        #pragma unroll
        for (int c = 0; c < NBUCKP / 64; ++c) {
            int idx = c * 64 + lane;
            int v = hist[idx];
            int xv = v;
            #pragma unroll
            for (int d = 1; d < 64; d <<= 1) {
                int t = __shfl_up(xv, d); if (lane >= d) xv += t;
            }
            lstart[idx] = xv - v + carry;
            carry += __shfl(xv, 63);
        }
    }
    __syncthreads();
    for (int i = tid; i < NBUCKP; i += 512) {
        cur[i] = lstart[i];
        if (hist[i] > 0) goff[i] = atomicAdd(&bcur0[i], hist[i]);
    }
    __syncthreads();
    for (int i = tid; i < cnt; i += 512) {
        int d = dst[e0 + i];
        int s = src[e0 + i];
        int b = d >> 6;
        int p = atomicAdd(&cur[b], 1);
        sorted[p] = ((d & 63) << 17) | s;
        sbkt[p] = (unsigned short)b;
    }
    __syncthreads();
    for (int i = tid; i < cnt; i += 512) {
        int b = sbkt[i];
        packed2[(size_t)b * ACAP + goff[b] + (i - lstart[b])] = sorted[i];
    }
}

// ---------------------------------------------------------------------------
// Kernel B: fused per-bucket sort + gather + MFMA MLP.  256 thr = 4 waves,
// one block per 64-node bucket (~16 KB LDS -> 8 blocks/CU = 32 waves/CU).
// Lean R13 8-acc gather loop (no predication — R14's 16-deep predicated
// variant cost VALU 57% and regressed).
// ---------------------------------------------------------------------------
__global__ __launch_bounds__(256) void bucket_fused(
    const unsigned short* __restrict__ xb,
    const int* __restrict__ packed2, const int* __restrict__ bcur0,
    const unsigned short* __restrict__ w1t, const unsigned short* __restrict__ w2t,
    const float* __restrict__ b1, const float* __restrict__ b2,
    const float* __restrict__ Wg, const float* __restrict__ bg,
    unsigned short* __restrict__ h_out, float* __restrict__ gate_out, int N)
{
    __shared__ int hist[64], excl[65], cur[64];
    __shared__ int stage[STCAP];
    __shared__ unsigned short vt[64][72];      // pad 64->72: conflict-free b128

    int tid = threadIdx.x;
    int lane = tid & 63;
    int wave = tid >> 6;                       // 0..3
    int b = blockIdx.x;
    int node0 = b * 64;
    int ecnt = bcur0[b];
    if (ecnt > ACAP) ecnt = ACAP;
    const int* arena = packed2 + (size_t)b * ACAP;

    // ---- phase 1: counting sort by local dst ----
    if (tid < 64) hist[tid] = 0;
    __syncthreads();
    for (int i = tid; i < ecnt; i += 256)
        atomicAdd(&hist[arena[i] >> 17], 1);
    __syncthreads();
    if (tid < 64) {
        int v = hist[lane];
        int xv = v;
        #pragma unroll
        for (int d = 1; d < 64; d <<= 1) {
            int t = __shfl_up(xv, d); if (lane >= d) xv += t;
        }
        excl[lane] = xv - v;
        if (lane == 63) excl[64] = xv;
        cur[lane] = xv - v;
    }
    __syncthreads();
    for (int i = tid; i < ecnt; i += 256) {
        int v = arena[i];
        int p = atomicAdd(&cur[v >> 17], 1);
        if (p < STCAP) stage[p] = v & 0x1FFFF;
    }
    __syncthreads();

    // ---- phase 2: gather 16 consecutive nodes per wave (8-acc ILP) ----
    int rowbase = wave * 16;
    for (int m = 0; m < 16; ++m) {
        int ln = rowbase + m;
        int node = node0 + ln;
        if (node < N) {
            int beg = excl[ln];     if (beg > STCAP) beg = STCAP;
            int end = excl[ln + 1]; if (end > STCAP) end = STCAP;

            float v0 = bf2f(xb[(size_t)node * 64 + lane]);   // self term
            float v1 = 0.f, v2 = 0.f, v3 = 0.f, v4 = 0.f, v5 = 0.f, v6 = 0.f, v7 = 0.f;

            for (int base = beg; base < end; base += 64) {
                int ei = (base + lane < end) ? stage[base + lane] : 0;
                int cnt = end - base; if (cnt > 64) cnt = 64;
                int j = 0;
                for (; j + 8 <= cnt; j += 8) {
                    int s0 = __builtin_amdgcn_readlane(ei, j + 0);
                    int s1 = __builtin_amdgcn_readlane(ei, j + 1);
                    int s2 = __builtin_amdgcn_readlane(ei, j + 2);
                    int s3 = __builtin_amdgcn_readlane(ei, j + 3);
                    int s4 = __builtin_amdgcn_readlane(ei, j + 4);
                    int s5 = __builtin_amdgcn_readlane(ei, j + 5);
                    int s6 = __builtin_amdgcn_readlane(ei, j + 6);
                    int s7 = __builtin_amdgcn_readlane(ei, j + 7);
                    unsigned short t0 = xb[(size_t)s0 * 64 + lane];
                    unsigned short t1 = xb[(size_t)s1 * 64 + lane];
                    unsigned short t2 = xb[(size_t)s2 * 64 + lane];
                    unsigned short t3 = xb[(size_t)s3 * 64 + lane];
                    unsigned short t4 = xb[(size_t)s4 * 64 + lane];
                    unsigned short t5 = xb[(size_t)s5 * 64 + lane];
                    unsigned short t6 = xb[(size_t)s6 * 64 + lane];
                    unsigned short t7 = xb[(size_t)s7 * 64 + lane];
                    v0 += bf2f(t0); v1 += bf2f(t1); v2 += bf2f(t2); v3 += bf2f(t3);
                    v4 += bf2f(t4); v5 += bf2f(t5); v6 += bf2f(t6); v7 += bf2f(t7);
                }
                for (; j < cnt; ++j) {
                    int s = __builtin_amdgcn_readlane(ei, j);
                    v1 += bf2f(xb[(size_t)s * 64 + lane]);
                }
            }
            float v = ((v0 + v1) + (v2 + v3)) + ((v4 + v5) + (v6 + v7));
            vt[ln][lane] = f2bf(v);
        } else {
            vt[ln][lane] = 0;
        }
    }
    // no barrier: phase 3 reads only this wave's own rows (same-wave DS order)

    // ---- phase 3: 16-node MFMA MLP on own tile ----
    {
        int quad = lane >> 4;
        int col  = lane & 15;

        s16x8 a0 = *(const s16x8*)&vt[rowbase + col][quad * 8];
        s16x8 a1 = *(const s16x8*)&vt[rowbase + col][32 + quad * 8];

        float b1v[4], b2v[4], wgv[4];
        #pragma unroll
        for (int nt = 0; nt < 4; ++nt) {
            b1v[nt] = b1[nt * 16 + col];
            b2v[nt] = b2[nt * 16 + col];
            wgv[nt] = Wg[nt * 16 + col];
        }
        float bgv = bg[0];

        f32x4 acc1[4];
        #pragma unroll
        for (int nt = 0; nt < 4; ++nt) {
            int off = (nt * 16 + col) * 64 + quad * 8;
            s16x8 w0 = *(const s16x8*)(w1t + off);
            s16x8 w1 = *(const s16x8*)(w1t + off + 32);
            f32x4 c = {0.f, 0.f, 0.f, 0.f};
            c = __builtin_amdgcn_mfma_f32_16x16x32_bf16(a0, w0, c, 0, 0, 0);
            c = __builtin_amdgcn_mfma_f32_16x16x32_bf16(a1, w1, c, 0, 0, 0);
            acc1[nt] = c;
        }
        #pragma unroll
        for (int nt = 0; nt < 4; ++nt)
            #pragma unroll
            for (int r = 0; r < 4; ++r) {
                float hv = fmaxf(acc1[nt][r] + b1v[nt], 0.f);
                vt[rowbase + quad * 4 + r][nt * 16 + col] = f2bf(hv);
            }

        s16x8 g0 = *(const s16x8*)&vt[rowbase + col][quad * 8];
        s16x8 g1 = *(const s16x8*)&vt[rowbase + col][32 + quad * 8];

        f32x4 acc2[4];
        #pragma unroll
        for (int nt = 0; nt < 4; ++nt) {
            int off = (nt * 16 + col) * 64 + quad * 8;
            s16x8 w0 = *(const s16x8*)(w2t + off);
            s16x8 w1 = *(const s16x8*)(w2t + off + 32);
            f32x4 c = {0.f, 0.f, 0.f, 0.f};
            c = __builtin_amdgcn_mfma_f32_16x16x32_bf16(g0, w0, c, 0, 0, 0);
            c = __builtin_amdgcn_mfma_f32_16x16x32_bf16(g1, w1, c, 0, 0, 0);
            acc2[nt] = c;
        }

        int nbase = node0 + rowbase;
        float gp[4] = {0.f, 0.f, 0.f, 0.f};
        #pragma unroll
        for (int nt = 0; nt < 4; ++nt)
            #pragma unroll
            for (int r = 0; r < 4; ++r) {
                float hv = fmaxf(acc2[nt][r] + b2v[nt], 0.f);
                int node = nbase + quad * 4 + r;
                if (node < N)
                    h_out[(size_t)node * 64 + nt * 16 + col] = f2bf(hv);
                gp[r] = fmaf(hv, wgv[nt], gp[r]);
            }
        #pragma unroll
        for (int r = 0; r < 4; ++r) {
            float t = gp[r];
            t += __shfl_xor(t, 1);
            t += __shfl_xor(t, 2);
            t += __shfl_xor(t, 4);
            t += __shfl_xor(t, 8);
            int node = nbase + quad * 4 + r;
            if (col == 0 && node < N) gate_out[node] = t + bgv;
        }
    }
}

// ---------------------------------------------------------------------------
// Kernel C: per-graph softmax-attention pooling + BN(eval) + linear + lsm.
// ---------------------------------------------------------------------------
__global__ __launch_bounds__(256) void pool_final(
    const unsigned short* __restrict__ h, const float* __restrict__ gate,
    const int* __restrict__ batch,
    const float* __restrict__ gamma_, const float* __restrict__ beta_,
    const float* __restrict__ mean_, const float* __restrict__ var_,
    const float* __restrict__ Wl, const float* __restrict__ bl,
    float* __restrict__ out, int N)
{
    int g = blockIdx.x;
    int tid = threadIdx.x;

    int lo = 0, hi = N;
    while (lo < hi) { int mid = (lo + hi) >> 1; if (batch[mid] < g) lo = mid + 1; else hi = mid; }
    int start = lo;
    hi = N;
    while (lo < hi) { int mid = (lo + hi) >> 1; if (batch[mid] < g + 1) lo = mid + 1; else hi = mid; }
    int end = lo;

    __shared__ float red[4];
    __shared__ float pool_s[4 * 64];

    int lane = tid & 63;
    int wave = tid >> 6;

    float m = -FLT_MAX;
    for (int i = start + tid; i < end; i += 256) m = fmaxf(m, gate[i]);
    #pragma unroll
    for (int off = 32; off; off >>= 1) m = fmaxf(m, __shfl_xor(m, off));
    if (lane == 0) red[wave] = m;
    __syncthreads();
    m = fmaxf(fmaxf(red[0], red[1]), fmaxf(red[2], red[3]));
    __syncthreads();

    float s = 0.f;
    for (int i = start + tid; i < end; i += 256) s += expf(gate[i] - m);
    #pragma unroll
    for (int off = 32; off; off >>= 1) s += __shfl_xor(s, off);
    if (lane == 0) red[wave] = s;
    __syncthreads();
    s = red[0] + red[1] + red[2] + red[3];

    float a0 = 0.f, a1 = 0.f, a2 = 0.f, a3 = 0.f;
    int i = start + wave;
    for (; i + 12 < end; i += 16) {
        float e0 = expf(gate[i]      - m);
        float e1 = expf(gate[i + 4]  - m);
        float e2 = expf(gate[i + 8]  - m);
        float e3 = expf(gate[i + 12] - m);
        float t0 = bf2f(h[(size_t)(i)      * 64 + lane]);
        float t1 = bf2f(h[(size_t)(i + 4)  * 64 + lane]);
        float t2 = bf2f(h[(size_t)(i + 8)  * 64 + lane]);
        float t3 = bf2f(h[(size_t)(i + 12) * 64 + lane]);
        a0 = fmaf(e0, t0, a0);
        a1 = fmaf(e1, t1, a1);
        a2 = fmaf(e2, t2, a2);
        a3 = fmaf(e3, t3, a3);
    }
    for (; i < end; i += 4) {
        float e = expf(gate[i] - m);
        a0 = fmaf(e, bf2f(h[(size_t)i * 64 + lane]), a0);
    }
    pool_s[wave * 64 + lane] = (a0 + a1) + (a2 + a3);
    __syncthreads();

    if (wave == 0) {
        float p = pool_s[lane] + pool_s[64 + lane] + pool_s[128 + lane] + pool_s[192 + lane];
        p = (end > start) ? (p / s) : 0.f;
        float nrm = (p - mean_[lane]) / sqrtf(var_[lane] + BN_EPS) * gamma_[lane] + beta_[lane];
        float l0 = nrm * Wl[lane * 2 + 0];
        float l1 = nrm * Wl[lane * 2 + 1];
        #pragma unroll
        for (int off = 32; off; off >>= 1) {
            l0 += __shfl_xor(l0, off);
            l1 += __shfl_xor(l1, off);
        }
        if (lane == 0) {
            l0 += bl[0];
            l1 += bl[1];
            float mx = fmaxf(l0, l1);
            float lse = mx + logf(expf(l0 - mx) + expf(l1 - mx));
            out[g * 2 + 0] = l0 - lse;
            out[g * 2 + 1] = l1 - lse;
        }
    }
}

// ---------------------------------------------------------------------------
extern "C" void kernel_launch(void* const* d_in, const int* in_sizes, int n_in,
                              void* d_out, int out_size, void* d_ws, size_t ws_size,
                              hipStream_t stream)
{
    const float* x     = (const float*)d_in[0];
    const int*   eidx  = (const int*)d_in[1];   // [2, E]: row0=src, row1=dst
    const int*   batch = (const int*)d_in[2];
    const float* W1    = (const float*)d_in[3];
    const float* b1    = (const float*)d_in[4];
    const float* W2    = (const float*)d_in[5];
    const float* b2    = (const float*)d_in[6];
    const float* Wg    = (const float*)d_in[7];
    const float* bg    = (const float*)d_in[8];
    const float* bng   = (const float*)d_in[9];
    const float* bnb   = (const float*)d_in[10];
    const float* bnm   = (const float*)d_in[11];
    const float* bnv   = (const float*)d_in[12];
    const float* Wl    = (const float*)d_in[13];
    const float* bl    = (const float*)d_in[14];
    float* out = (float*)d_out;

    int N = in_sizes[0] / 64;        // requires N < 131072 (17-bit src pack)
    int E = in_sizes[1] / 2;
    int G = out_size / 2;
    int NP = ((N + 63) / 64) * 64;
    int NBUCK = (N + 63) / 64;       // <= NBUCKP
    int EB = (E + PBLK - 1) / PBLK;
    int GRID_A = 1024 > EB ? 1024 : EB;

    char* w = (char*)d_ws;
    int* packed2 = (int*)w;                     w += (size_t)NBUCK * ACAP * 4;
    unsigned short* hxb  = (unsigned short*)w;  w += (size_t)NP * 64 * 2;   // xb
    float* gate  = (float*)w;                   w += ((size_t)N * 4 + 255) / 256 * 256;
    int* bcur0   = (int*)w;                     w += NBUCKP * 4;
    unsigned short* w1t = (unsigned short*)w;   w += 4096 * 2;
    unsigned short* w2t = (unsigned short*)w;   w += 4096 * 2;
    unsigned short* hbuf = (unsigned short*)w;  // N*64 bf16 (dedicated h)

    const int* src = eidx;
    const int* dst = eidx + E;

    hipMemsetAsync(bcur0, 0, NBUCKP * sizeof(int), stream);

    prep_partition<<<GRID_A, 512, 0, stream>>>(x, hxb, W1, W2, w1t, w2t,
                                               src, dst, bcur0, packed2,
                                               N, E, EB);

    bucket_fused  <<<NBUCK, 256, 0, stream>>>(hxb, packed2, bcur0, w1t, w2t,
                                              b1, b2, Wg, bg, hbuf, gate, N);

    pool_final    <<<G, 256, 0, stream>>>(hbuf, gate, batch, bng, bnb, bnm, bnv,
                                          Wl, bl, out, N);
}

// Round 17
// 212.645 us; speedup vs baseline: 1.0975x; 1.0975x over previous
//
#include <hip/hip_runtime.h>
#include <math.h>
#include <float.h>

#define BN_EPS 1e-5f
#define PBLK   8192      // edges per partition block
#define NBUCKP 832       // padded bucket count (scan width; N <= 106496)
#define ACAP   4096      // arena ints per 128-node bucket
#define STCAP  3072      // LDS stage capacity (expected bucket max ~2350)

typedef short s16x8 __attribute__((ext_vector_type(8)));
typedef float f32x4 __attribute__((ext_vector_type(4)));

__device__ __forceinline__ unsigned short f2bf(float f) {
    unsigned u = __float_as_uint(f);
    u += 0x7FFFu + ((u >> 16) & 1u);          // round-to-nearest-even
    return (unsigned short)(u >> 16);
}
__device__ __forceinline__ float bf2f(unsigned short b) {
    return __uint_as_float(((unsigned)b) << 16);
}

// ---------------------------------------------------------------------------
// Kernel A: prep + partition (R15 winner, verbatim).  1024 blocks share the
// xb conversion; blocks < EB partition edges (bucket = dst>>7).
// val = (dst&127)<<17 | src  (requires N < 131072).
// ---------------------------------------------------------------------------
__global__ __launch_bounds__(512) void prep_partition(
    const float* __restrict__ x, unsigned short* __restrict__ xb,
    const float* __restrict__ W1, const float* __restrict__ W2,
    unsigned short* __restrict__ w1t, unsigned short* __restrict__ w2t,
    const int* __restrict__ src, const int* __restrict__ dst,
    int* __restrict__ bcur0, int* __restrict__ packed2,
    int N, int E, int EB)
{
    __shared__ int hist[NBUCKP], lstart[NBUCKP], goff[NBUCKP], cur[NBUCKP];
    __shared__ int sorted[PBLK];
    __shared__ unsigned short sbkt[PBLK];

    int tid = threadIdx.x;
    int lane = tid & 63;
    int blk = blockIdx.x;

    // --- xb conversion (grid-strided over ALL blocks) ---
    int n4 = N * 16;
    for (int i = blk * 512 + tid; i < n4; i += gridDim.x * 512) {
        float4 f = *(const float4*)(x + (size_t)i * 4);
        ushort4 o;
        o.x = f2bf(f.x); o.y = f2bf(f.y); o.z = f2bf(f.z); o.w = f2bf(f.w);
        *(ushort4*)(xb + (size_t)i * 4) = o;
    }
    if (blk == 0)
        for (int idx = tid; idx < 4096; idx += 512)
            w1t[idx] = f2bf(W1[(idx & 63) * 64 + (idx >> 6)]);
    if (blk == 1)
        for (int idx = tid; idx < 4096; idx += 512)
            w2t[idx] = f2bf(W2[(idx & 63) * 64 + (idx >> 6)]);

    if (blk >= EB) return;

    // --- edge partition (blocks < EB only) ---
    int e0 = blk * PBLK;
    int cnt = E - e0; if (cnt > PBLK) cnt = PBLK; if (cnt < 0) cnt = 0;

    for (int i = tid; i < NBUCKP; i += 512) hist[i] = 0;
    __syncthreads();
    for (int i = tid; i < cnt; i += 512)
        atomicAdd(&hist[dst[e0 + i] >> 7], 1);
    __syncthreads();
    if (tid < 64) {
        int carry = 0;
        #pragma unroll
        for (int c = 0; c < NBUCKP / 64; ++c) {
            int idx = c * 64 + lane;
            int v = hist[idx];
            int xv = v;
            #pragma unroll
            for (int d = 1; d < 64; d <<= 1) {
                int t = __shfl_up(xv, d); if (lane >= d) xv += t;
            }
            lstart[idx] = xv - v + carry;
            carry += __shfl(xv, 63);
        }
    }
    __syncthreads();
    for (int i = tid; i < NBUCKP; i += 512) {
        cur[i] = lstart[i];
        if (hist[i] > 0) goff[i] = atomicAdd(&bcur0[i], hist[i]);
    }
    __syncthreads();
    for (int i = tid; i < cnt; i += 512) {
        int d = dst[e0 + i];
        int s = src[e0 + i];
        int b = d >> 7;
        int p = atomicAdd(&cur[b], 1);
        sorted[p] = ((d & 127) << 17) | s;
        sbkt[p] = (unsigned short)b;
    }
    __syncthreads();
    for (int i = tid; i < cnt; i += 512) {
        int b = sbkt[i];
        packed2[(size_t)b * ACAP + goff[b] + (i - lstart[b])] = sorted[i];
    }
}

// ---------------------------------------------------------------------------
// Kernel B: fused per-bucket sort + gather + MFMA MLP.  1024 thr = 16 waves,
// one block per 128-node bucket (R16 post-mortem: 782 blocks = 3/CU of work
// was the occupancy limit at 512 thr; 16 waves/block -> 2 blocks/CU = 32
// waves/CU = full).  Phase 2: each wave gathers 8 nodes (lean 8-acc loop).
// One barrier, then waves 0-7 run the 16-node MFMA tiles.
// ---------------------------------------------------------------------------
__global__ __launch_bounds__(1024, 8) void bucket_fused(
    const unsigned short* __restrict__ xb,
    const int* __restrict__ packed2, const int* __restrict__ bcur0,
    const unsigned short* __restrict__ w1t, const unsigned short* __restrict__ w2t,
    const float* __restrict__ b1, const float* __restrict__ b2,
    const float* __restrict__ Wg, const float* __restrict__ bg,
    unsigned short* __restrict__ h_out, float* __restrict__ gate_out, int N)
{
    __shared__ int hist[128], excl[129], cur[128];
    __shared__ int stage[STCAP];
    __shared__ unsigned short vt[128][72];     // pad 64->72: conflict-free b128

    int tid = threadIdx.x;
    int lane = tid & 63;
    int wave = tid >> 6;                       // 0..15
    int b = blockIdx.x;
    int node0 = b * 128;
    int ecnt = bcur0[b];
    if (ecnt > ACAP) ecnt = ACAP;
    const int* arena = packed2 + (size_t)b * ACAP;

    // ---- phase 1: counting sort by local dst ----
    if (tid < 128) hist[tid] = 0;
    __syncthreads();
    for (int i = tid; i < ecnt; i += 1024)
        atomicAdd(&hist[arena[i] >> 17], 1);
    __syncthreads();
    if (tid < 64) {
        int carry = 0;
        #pragma unroll
        for (int c = 0; c < 2; ++c) {
            int idx = c * 64 + lane;
            int v = hist[idx];
            int xv = v;
            #pragma unroll
            for (int d = 1; d < 64; d <<= 1) {
                int t = __shfl_up(xv, d); if (lane >= d) xv += t;
            }
            excl[idx] = xv - v + carry;
            carry += __shfl(xv, 63);
        }
        if (lane == 0) excl[128] = carry;
    }
    __syncthreads();
    if (tid < 128) cur[tid] = excl[tid];
    __syncthreads();
    for (int i = tid; i < ecnt; i += 1024) {
        int v = arena[i];
        int p = atomicAdd(&cur[v >> 17], 1);
        if (p < STCAP) stage[p] = v & 0x1FFFF;
    }
    __syncthreads();

    // ---- phase 2: gather 8 consecutive nodes per wave (8-acc ILP) ----
    int rowbase = wave * 8;
    for (int m = 0; m < 8; ++m) {
        int ln = rowbase + m;
        int node = node0 + ln;
        if (node < N) {
            int beg = excl[ln];     if (beg > STCAP) beg = STCAP;
            int end = excl[ln + 1]; if (end > STCAP) end = STCAP;

            float v0 = bf2f(xb[(size_t)node * 64 + lane]);   // self term
            float v1 = 0.f, v2 = 0.f, v3 = 0.f, v4 = 0.f, v5 = 0.f, v6 = 0.f, v7 = 0.f;

            for (int base = beg; base < end; base += 64) {
                int ei = (base + lane < end) ? stage[base + lane] : 0;
                int cnt = end - base; if (cnt > 64) cnt = 64;
                int j = 0;
                for (; j + 8 <= cnt; j += 8) {
                    int s0 = __builtin_amdgcn_readlane(ei, j + 0);
                    int s1 = __builtin_amdgcn_readlane(ei, j + 1);
                    int s2 = __builtin_amdgcn_readlane(ei, j + 2);
                    int s3 = __builtin_amdgcn_readlane(ei, j + 3);
                    int s4 = __builtin_amdgcn_readlane(ei, j + 4);
                    int s5 = __builtin_amdgcn_readlane(ei, j + 5);
                    int s6 = __builtin_amdgcn_readlane(ei, j + 6);
                    int s7 = __builtin_amdgcn_readlane(ei, j + 7);
                    unsigned short t0 = xb[(size_t)s0 * 64 + lane];
                    unsigned short t1 = xb[(size_t)s1 * 64 + lane];
                    unsigned short t2 = xb[(size_t)s2 * 64 + lane];
                    unsigned short t3 = xb[(size_t)s3 * 64 + lane];
                    unsigned short t4 = xb[(size_t)s4 * 64 + lane];
                    unsigned short t5 = xb[(size_t)s5 * 64 + lane];
                    unsigned short t6 = xb[(size_t)s6 * 64 + lane];
                    unsigned short t7 = xb[(size_t)s7 * 64 + lane];
                    v0 += bf2f(t0); v1 += bf2f(t1); v2 += bf2f(t2); v3 += bf2f(t3);
                    v4 += bf2f(t4); v5 += bf2f(t5); v6 += bf2f(t6); v7 += bf2f(t7);
                }
                for (; j < cnt; ++j) {
                    int s = __builtin_amdgcn_readlane(ei, j);
                    v1 += bf2f(xb[(size_t)s * 64 + lane]);
                }
            }
            float v = ((v0 + v1) + (v2 + v3)) + ((v4 + v5) + (v6 + v7));
            vt[ln][lane] = f2bf(v);
        } else {
            vt[ln][lane] = 0;
        }
    }
    __syncthreads();   // phase 3 tiles span rows gathered by two waves

    // ---- phase 3: waves 0-7 run 16-node MFMA MLP tiles ----
    if (wave < 8) {
        int rb3 = wave * 16;
        int quad = lane >> 4;
        int col  = lane & 15;

        s16x8 a0 = *(const s16x8*)&vt[rb3 + col][quad * 8];
        s16x8 a1 = *(const s16x8*)&vt[rb3 + col][32 + quad * 8];

        float b1v[4], b2v[4], wgv[4];
        #pragma unroll
        for (int nt = 0; nt < 4; ++nt) {
            b1v[nt] = b1[nt * 16 + col];
            b2v[nt] = b2[nt * 16 + col];
            wgv[nt] = Wg[nt * 16 + col];
        }
        float bgv = bg[0];

        f32x4 acc1[4];
        #pragma unroll
        for (int nt = 0; nt < 4; ++nt) {
            int off = (nt * 16 + col) * 64 + quad * 8;
            s16x8 w0 = *(const s16x8*)(w1t + off);
            s16x8 w1 = *(const s16x8*)(w1t + off + 32);
            f32x4 c = {0.f, 0.f, 0.f, 0.f};
            c = __builtin_amdgcn_mfma_f32_16x16x32_bf16(a0, w0, c, 0, 0, 0);
            c = __builtin_amdgcn_mfma_f32_16x16x32_bf16(a1, w1, c, 0, 0, 0);
            acc1[nt] = c;
        }
        #pragma unroll
        for (int nt = 0; nt < 4; ++nt)
            #pragma unroll
            for (int r = 0; r < 4; ++r) {
                float hv = fmaxf(acc1[nt][r] + b1v[nt], 0.f);
                vt[rb3 + quad * 4 + r][nt * 16 + col] = f2bf(hv);
            }

        s16x8 g0 = *(const s16x8*)&vt[rb3 + col][quad * 8];
        s16x8 g1 = *(const s16x8*)&vt[rb3 + col][32 + quad * 8];

        f32x4 acc2[4];
        #pragma unroll
        for (int nt = 0; nt < 4; ++nt) {
            int off = (nt * 16 + col) * 64 + quad * 8;
            s16x8 w0 = *(const s16x8*)(w2t + off);
            s16x8 w1 = *(const s16x8*)(w2t + off + 32);
            f32x4 c = {0.f, 0.f, 0.f, 0.f};
            c = __builtin_amdgcn_mfma_f32_16x16x32_bf16(g0, w0, c, 0, 0, 0);
            c = __builtin_amdgcn_mfma_f32_16x16x32_bf16(g1, w1, c, 0, 0, 0);
            acc2[nt] = c;
        }

        int nbase = node0 + rb3;
        float gp[4] = {0.f, 0.f, 0.f, 0.f};
        #pragma unroll
        for (int nt = 0; nt < 4; ++nt)
            #pragma unroll
            for (int r = 0; r < 4; ++r) {
                float hv = fmaxf(acc2[nt][r] + b2v[nt], 0.f);
                int node = nbase + quad * 4 + r;
                if (node < N)
                    h_out[(size_t)node * 64 + nt * 16 + col] = f2bf(hv);
                gp[r] = fmaf(hv, wgv[nt], gp[r]);
            }
        #pragma unroll
        for (int r = 0; r < 4; ++r) {
            float t = gp[r];
            t += __shfl_xor(t, 1);
            t += __shfl_xor(t, 2);
            t += __shfl_xor(t, 4);
            t += __shfl_xor(t, 8);
            int node = nbase + quad * 4 + r;
            if (col == 0 && node < N) gate_out[node] = t + bgv;
        }
    }
}

// ---------------------------------------------------------------------------
// Kernel C: per-graph softmax-attention pooling + BN(eval) + linear + lsm.
// ---------------------------------------------------------------------------
__global__ __launch_bounds__(256) void pool_final(
    const unsigned short* __restrict__ h, const float* __restrict__ gate,
    const int* __restrict__ batch,
    const float* __restrict__ gamma_, const float* __restrict__ beta_,
    const float* __restrict__ mean_, const float* __restrict__ var_,
    const float* __restrict__ Wl, const float* __restrict__ bl,
    float* __restrict__ out, int N)
{
    int g = blockIdx.x;
    int tid = threadIdx.x;

    int lo = 0, hi = N;
    while (lo < hi) { int mid = (lo + hi) >> 1; if (batch[mid] < g) lo = mid + 1; else hi = mid; }
    int start = lo;
    hi = N;
    while (lo < hi) { int mid = (lo + hi) >> 1; if (batch[mid] < g + 1) lo = mid + 1; else hi = mid; }
    int end = lo;

    __shared__ float red[4];
    __shared__ float pool_s[4 * 64];

    int lane = tid & 63;
    int wave = tid >> 6;

    float m = -FLT_MAX;
    for (int i = start + tid; i < end; i += 256) m = fmaxf(m, gate[i]);
    #pragma unroll
    for (int off = 32; off; off >>= 1) m = fmaxf(m, __shfl_xor(m, off));
    if (lane == 0) red[wave] = m;
    __syncthreads();
    m = fmaxf(fmaxf(red[0], red[1]), fmaxf(red[2], red[3]));
    __syncthreads();

    float s = 0.f;
    for (int i = start + tid; i < end; i += 256) s += expf(gate[i] - m);
    #pragma unroll
    for (int off = 32; off; off >>= 1) s += __shfl_xor(s, off);
    if (lane == 0) red[wave] = s;
    __syncthreads();
    s = red[0] + red[1] + red[2] + red[3];

    float a0 = 0.f, a1 = 0.f, a2 = 0.f, a3 = 0.f;
    int i = start + wave;
    for (; i + 12 < end; i += 16) {
        float e0 = expf(gate[i]      - m);
        float e1 = expf(gate[i + 4]  - m);
        float e2 = expf(gate[i + 8]  - m);
        float e3 = expf(gate[i + 12] - m);
        float t0 = bf2f(h[(size_t)(i)      * 64 + lane]);
        float t1 = bf2f(h[(size_t)(i + 4)  * 64 + lane]);
        float t2 = bf2f(h[(size_t)(i + 8)  * 64 + lane]);
        float t3 = bf2f(h[(size_t)(i + 12) * 64 + lane]);
        a0 = fmaf(e0, t0, a0);
        a1 = fmaf(e1, t1, a1);
        a2 = fmaf(e2, t2, a2);
        a3 = fmaf(e3, t3, a3);
    }
    for (; i < end; i += 4) {
        float e = expf(gate[i] - m);
        a0 = fmaf(e, bf2f(h[(size_t)i * 64 + lane]), a0);
    }
    pool_s[wave * 64 + lane] = (a0 + a1) + (a2 + a3);
    __syncthreads();

    if (wave == 0) {
        float p = pool_s[lane] + pool_s[64 + lane] + pool_s[128 + lane] + pool_s[192 + lane];
        p = (end > start) ? (p / s) : 0.f;
        float nrm = (p - mean_[lane]) / sqrtf(var_[lane] + BN_EPS) * gamma_[lane] + beta_[lane];
        float l0 = nrm * Wl[lane * 2 + 0];
        float l1 = nrm * Wl[lane * 2 + 1];
        #pragma unroll
        for (int off = 32; off; off >>= 1) {
            l0 += __shfl_xor(l0, off);
            l1 += __shfl_xor(l1, off);
        }
        if (lane == 0) {
            l0 += bl[0];
            l1 += bl[1];
            float mx = fmaxf(l0, l1);
            float lse = mx + logf(expf(l0 - mx) + expf(l1 - mx));
            out[g * 2 + 0] = l0 - lse;
            out[g * 2 + 1] = l1 - lse;
        }
    }
}

// ---------------------------------------------------------------------------
extern "C" void kernel_launch(void* const* d_in, const int* in_sizes, int n_in,
                              void* d_out, int out_size, void* d_ws, size_t ws_size,
                              hipStream_t stream)
{
    const float* x     = (const float*)d_in[0];
    const int*   eidx  = (const int*)d_in[1];   // [2, E]: row0=src, row1=dst
    const int*   batch = (const int*)d_in[2];
    const float* W1    = (const float*)d_in[3];
    const float* b1    = (const float*)d_in[4];
    const float* W2    = (const float*)d_in[5];
    const float* b2    = (const float*)d_in[6];
    const float* Wg    = (const float*)d_in[7];
    const float* bg    = (const float*)d_in[8];
    const float* bng   = (const float*)d_in[9];
    const float* bnb   = (const float*)d_in[10];
    const float* bnm   = (const float*)d_in[11];
    const float* bnv   = (const float*)d_in[12];
    const float* Wl    = (const float*)d_in[13];
    const float* bl    = (const float*)d_in[14];
    float* out = (float*)d_out;

    int N = in_sizes[0] / 64;        // requires N < 131072 (17-bit src pack)
    int E = in_sizes[1] / 2;
    int G = out_size / 2;
    int NP = ((N + 63) / 64) * 64;
    int NBUCK = (N + 127) / 128;     // <= NBUCKP
    int EB = (E + PBLK - 1) / PBLK;
    int GRID_A = 1024 > EB ? 1024 : EB;

    char* w = (char*)d_ws;
    int* packed2 = (int*)w;                     w += (size_t)NBUCK * ACAP * 4;
    unsigned short* hxb  = (unsigned short*)w;  w += (size_t)NP * 64 * 2;   // xb
    float* gate  = (float*)w;                   w += ((size_t)N * 4 + 255) / 256 * 256;
    int* bcur0   = (int*)w;                     w += NBUCKP * 4;
    unsigned short* w1t = (unsigned short*)w;   w += 4096 * 2;
    unsigned short* w2t = (unsigned short*)w;   w += 4096 * 2;
    unsigned short* hbuf = (unsigned short*)w;  // N*64 bf16 (dedicated h)

    const int* src = eidx;
    const int* dst = eidx + E;

    hipMemsetAsync(bcur0, 0, NBUCKP * sizeof(int), stream);

    prep_partition<<<GRID_A, 512, 0, stream>>>(x, hxb, W1, W2, w1t, w2t,
                                               src, dst, bcur0, packed2,
                                               N, E, EB);

    bucket_fused  <<<NBUCK, 1024, 0, stream>>>(hxb, packed2, bcur0, w1t, w2t,
                                               b1, b2, Wg, bg, hbuf, gate, N);

    pool_final    <<<G, 256, 0, stream>>>(hbuf, gate, batch, bng, bnb, bnm, bnv,
                                          Wl, bl, out, N);
}

// Round 18
// 190.931 us; speedup vs baseline: 1.2223x; 1.1137x over previous
//
#include <hip/hip_runtime.h>
#include <math.h>
#include <float.h>

#define BN_EPS 1e-5f
#define PBLK   8192      // edges per partition block
#define NBUCKP 832       // padded bucket count (scan width; N <= 106496)
#define ACAP   4096      // arena ints per 128-node bucket
#define STCAP  3072      // LDS stage capacity (expected bucket max ~2350)

typedef short s16x8 __attribute__((ext_vector_type(8)));
typedef float f32x4 __attribute__((ext_vector_type(4)));

__device__ __forceinline__ unsigned short f2bf(float f) {
    unsigned u = __float_as_uint(f);
    u += 0x7FFFu + ((u >> 16) & 1u);          // round-to-nearest-even
    return (unsigned short)(u >> 16);
}
__device__ __forceinline__ float bf2f(unsigned short b) {
    return __uint_as_float(((unsigned)b) << 16);
}

// ---------------------------------------------------------------------------
// Kernel A: prep + partition (R15 winner).  1024 blocks share the xb
// conversion; blocks < EB partition edges (bucket = dst>>7).
// val = (dst&127)<<17 | src  (requires N < 131072).
// ---------------------------------------------------------------------------
__global__ __launch_bounds__(512) void prep_partition(
    const float* __restrict__ x, unsigned short* __restrict__ xb,
    const float* __restrict__ W1, const float* __restrict__ W2,
    unsigned short* __restrict__ w1t, unsigned short* __restrict__ w2t,
    const int* __restrict__ src, const int* __restrict__ dst,
    int* __restrict__ bcur0, int* __restrict__ packed2,
    int N, int E, int EB)
{
    __shared__ int hist[NBUCKP], lstart[NBUCKP], goff[NBUCKP], cur[NBUCKP];
    __shared__ int sorted[PBLK];
    __shared__ unsigned short sbkt[PBLK];

    int tid = threadIdx.x;
    int lane = tid & 63;
    int blk = blockIdx.x;

    // --- xb conversion (grid-strided over ALL blocks) ---
    int n4 = N * 16;
    for (int i = blk * 512 + tid; i < n4; i += gridDim.x * 512) {
        float4 f = *(const float4*)(x + (size_t)i * 4);
        ushort4 o;
        o.x = f2bf(f.x); o.y = f2bf(f.y); o.z = f2bf(f.z); o.w = f2bf(f.w);
        *(ushort4*)(xb + (size_t)i * 4) = o;
    }
    if (blk == 0)
        for (int idx = tid; idx < 4096; idx += 512)
            w1t[idx] = f2bf(W1[(idx & 63) * 64 + (idx >> 6)]);
    if (blk == 1)
        for (int idx = tid; idx < 4096; idx += 512)
            w2t[idx] = f2bf(W2[(idx & 63) * 64 + (idx >> 6)]);

    if (blk >= EB) return;

    // --- edge partition (blocks < EB only) ---
    int e0 = blk * PBLK;
    int cnt = E - e0; if (cnt > PBLK) cnt = PBLK; if (cnt < 0) cnt = 0;

    for (int i = tid; i < NBUCKP; i += 512) hist[i] = 0;
    __syncthreads();
    for (int i = tid; i < cnt; i += 512)
        atomicAdd(&hist[dst[e0 + i] >> 7], 1);
    __syncthreads();
    if (tid < 64) {
        int carry = 0;
        #pragma unroll
        for (int c = 0; c < NBUCKP / 64; ++c) {
            int idx = c * 64 + lane;
            int v = hist[idx];
            int xv = v;
            #pragma unroll
            for (int d = 1; d < 64; d <<= 1) {
                int t = __shfl_up(xv, d); if (lane >= d) xv += t;
            }
            lstart[idx] = xv - v + carry;
            carry += __shfl(xv, 63);
        }
    }
    __syncthreads();
    for (int i = tid; i < NBUCKP; i += 512) {
        cur[i] = lstart[i];
        if (hist[i] > 0) goff[i] = atomicAdd(&bcur0[i], hist[i]);
    }
    __syncthreads();
    for (int i = tid; i < cnt; i += 512) {
        int d = dst[e0 + i];
        int s = src[e0 + i];
        int b = d >> 7;
        int p = atomicAdd(&cur[b], 1);
        sorted[p] = ((d & 127) << 17) | s;
        sbkt[p] = (unsigned short)b;
    }
    __syncthreads();
    for (int i = tid; i < cnt; i += 512) {
        int b = sbkt[i];
        packed2[(size_t)b * ACAP + goff[b] + (i - lstart[b])] = sorted[i];
    }
}

// ---------------------------------------------------------------------------
// Kernel B: fused per-bucket sort + gather + MFMA MLP (R15 winner + 4-wide
// mid-batch in the gather remainder).  512 thr = 8 waves, one block per
// 128-node bucket.
// ---------------------------------------------------------------------------
__global__ __launch_bounds__(512) void bucket_fused(
    const unsigned short* __restrict__ xb,
    const int* __restrict__ packed2, const int* __restrict__ bcur0,
    const unsigned short* __restrict__ w1t, const unsigned short* __restrict__ w2t,
    const float* __restrict__ b1, const float* __restrict__ b2,
    const float* __restrict__ Wg, const float* __restrict__ bg,
    unsigned short* __restrict__ h_out, float* __restrict__ gate_out, int N)
{
    __shared__ int hist[128], excl[129], cur[128];
    __shared__ int stage[STCAP];
    __shared__ unsigned short vt[128][72];     // pad 64->72: conflict-free b128

    int tid = threadIdx.x;
    int lane = tid & 63;
    int wave = tid >> 6;                       // 0..7
    int b = blockIdx.x;
    int node0 = b * 128;
    int ecnt = bcur0[b];
    if (ecnt > ACAP) ecnt = ACAP;
    const int* arena = packed2 + (size_t)b * ACAP;

    // ---- phase 1: counting sort by local dst ----
    if (tid < 128) hist[tid] = 0;
    __syncthreads();
    for (int i = tid; i < ecnt; i += 512)
        atomicAdd(&hist[arena[i] >> 17], 1);
    __syncthreads();
    if (tid < 64) {
        int carry = 0;
        #pragma unroll
        for (int c = 0; c < 2; ++c) {
            int idx = c * 64 + lane;
            int v = hist[idx];
            int xv = v;
            #pragma unroll
            for (int d = 1; d < 64; d <<= 1) {
                int t = __shfl_up(xv, d); if (lane >= d) xv += t;
            }
            excl[idx] = xv - v + carry;
            carry += __shfl(xv, 63);
        }
        if (lane == 0) excl[128] = carry;
    }
    __syncthreads();
    if (tid < 128) cur[tid] = excl[tid];
    __syncthreads();
    for (int i = tid; i < ecnt; i += 512) {
        int v = arena[i];
        int p = atomicAdd(&cur[v >> 17], 1);
        if (p < STCAP) stage[p] = v & 0x1FFFF;
    }
    __syncthreads();

    // ---- phase 2: gather 16 consecutive nodes per wave (8/4-acc ILP) ----
    int rowbase = wave * 16;
    for (int m = 0; m < 16; ++m) {
        int ln = rowbase + m;
        int node = node0 + ln;
        if (node < N) {
            int beg = excl[ln];     if (beg > STCAP) beg = STCAP;
            int end = excl[ln + 1]; if (end > STCAP) end = STCAP;

            float v0 = bf2f(xb[(size_t)node * 64 + lane]);   // self term
            float v1 = 0.f, v2 = 0.f, v3 = 0.f, v4 = 0.f, v5 = 0.f, v6 = 0.f, v7 = 0.f;

            for (int base = beg; base < end; base += 64) {
                int ei = (base + lane < end) ? stage[base + lane] : 0;
                int cnt = end - base; if (cnt > 64) cnt = 64;
                int j = 0;
                for (; j + 8 <= cnt; j += 8) {
                    int s0 = __builtin_amdgcn_readlane(ei, j + 0);
                    int s1 = __builtin_amdgcn_readlane(ei, j + 1);
                    int s2 = __builtin_amdgcn_readlane(ei, j + 2);
                    int s3 = __builtin_amdgcn_readlane(ei, j + 3);
                    int s4 = __builtin_amdgcn_readlane(ei, j + 4);
                    int s5 = __builtin_amdgcn_readlane(ei, j + 5);
                    int s6 = __builtin_amdgcn_readlane(ei, j + 6);
                    int s7 = __builtin_amdgcn_readlane(ei, j + 7);
                    unsigned short t0 = xb[(size_t)s0 * 64 + lane];
                    unsigned short t1 = xb[(size_t)s1 * 64 + lane];
                    unsigned short t2 = xb[(size_t)s2 * 64 + lane];
                    unsigned short t3 = xb[(size_t)s3 * 64 + lane];
                    unsigned short t4 = xb[(size_t)s4 * 64 + lane];
                    unsigned short t5 = xb[(size_t)s5 * 64 + lane];
                    unsigned short t6 = xb[(size_t)s6 * 64 + lane];
                    unsigned short t7 = xb[(size_t)s7 * 64 + lane];
                    v0 += bf2f(t0); v1 += bf2f(t1); v2 += bf2f(t2); v3 += bf2f(t3);
                    v4 += bf2f(t4); v5 += bf2f(t5); v6 += bf2f(t6); v7 += bf2f(t7);
                }
                for (; j + 4 <= cnt; j += 4) {     // 4-wide mid-batch
                    int s0 = __builtin_amdgcn_readlane(ei, j + 0);
                    int s1 = __builtin_amdgcn_readlane(ei, j + 1);
                    int s2 = __builtin_amdgcn_readlane(ei, j + 2);
                    int s3 = __builtin_amdgcn_readlane(ei, j + 3);
                    unsigned short t0 = xb[(size_t)s0 * 64 + lane];
                    unsigned short t1 = xb[(size_t)s1 * 64 + lane];
                    unsigned short t2 = xb[(size_t)s2 * 64 + lane];
                    unsigned short t3 = xb[(size_t)s3 * 64 + lane];
                    v4 += bf2f(t0); v5 += bf2f(t1); v6 += bf2f(t2); v7 += bf2f(t3);
                }
                for (; j < cnt; ++j) {
                    int s = __builtin_amdgcn_readlane(ei, j);
                    v1 += bf2f(xb[(size_t)s * 64 + lane]);
                }
            }
            float v = ((v0 + v1) + (v2 + v3)) + ((v4 + v5) + (v6 + v7));
            vt[ln][lane] = f2bf(v);
        } else {
            vt[ln][lane] = 0;
        }
    }
    // no barrier: phase 3 reads only this wave's own rows (same-wave DS order)

    // ---- phase 3: 16-node MFMA MLP on own tile ----
    {
        int quad = lane >> 4;
        int col  = lane & 15;

        s16x8 a0 = *(const s16x8*)&vt[rowbase + col][quad * 8];
        s16x8 a1 = *(const s16x8*)&vt[rowbase + col][32 + quad * 8];

        float b1v[4], b2v[4], wgv[4];
        #pragma unroll
        for (int nt = 0; nt < 4; ++nt) {
            b1v[nt] = b1[nt * 16 + col];
            b2v[nt] = b2[nt * 16 + col];
            wgv[nt] = Wg[nt * 16 + col];
        }
        float bgv = bg[0];

        f32x4 acc1[4];
        #pragma unroll
        for (int nt = 0; nt < 4; ++nt) {
            int off = (nt * 16 + col) * 64 + quad * 8;
            s16x8 w0 = *(const s16x8*)(w1t + off);
            s16x8 w1 = *(const s16x8*)(w1t + off + 32);
            f32x4 c = {0.f, 0.f, 0.f, 0.f};
            c = __builtin_amdgcn_mfma_f32_16x16x32_bf16(a0, w0, c, 0, 0, 0);
            c = __builtin_amdgcn_mfma_f32_16x16x32_bf16(a1, w1, c, 0, 0, 0);
            acc1[nt] = c;
        }
        #pragma unroll
        for (int nt = 0; nt < 4; ++nt)
            #pragma unroll
            for (int r = 0; r < 4; ++r) {
                float hv = fmaxf(acc1[nt][r] + b1v[nt], 0.f);
                vt[rowbase + quad * 4 + r][nt * 16 + col] = f2bf(hv);
            }

        s16x8 g0 = *(const s16x8*)&vt[rowbase + col][quad * 8];
        s16x8 g1 = *(const s16x8*)&vt[rowbase + col][32 + quad * 8];

        f32x4 acc2[4];
        #pragma unroll
        for (int nt = 0; nt < 4; ++nt) {
            int off = (nt * 16 + col) * 64 + quad * 8;
            s16x8 w0 = *(const s16x8*)(w2t + off);
            s16x8 w1 = *(const s16x8*)(w2t + off + 32);
            f32x4 c = {0.f, 0.f, 0.f, 0.f};
            c = __builtin_amdgcn_mfma_f32_16x16x32_bf16(g0, w0, c, 0, 0, 0);
            c = __builtin_amdgcn_mfma_f32_16x16x32_bf16(g1, w1, c, 0, 0, 0);
            acc2[nt] = c;
        }

        int nbase = node0 + rowbase;
        float gp[4] = {0.f, 0.f, 0.f, 0.f};
        #pragma unroll
        for (int nt = 0; nt < 4; ++nt)
            #pragma unroll
            for (int r = 0; r < 4; ++r) {
                float hv = fmaxf(acc2[nt][r] + b2v[nt], 0.f);
                int node = nbase + quad * 4 + r;
                if (node < N)
                    h_out[(size_t)node * 64 + nt * 16 + col] = f2bf(hv);
                gp[r] = fmaf(hv, wgv[nt], gp[r]);
            }
        #pragma unroll
        for (int r = 0; r < 4; ++r) {
            float t = gp[r];
            t += __shfl_xor(t, 1);
            t += __shfl_xor(t, 2);
            t += __shfl_xor(t, 4);
            t += __shfl_xor(t, 8);
            int node = nbase + quad * 4 + r;
            if (col == 0 && node < N) gate_out[node] = t + bgv;
        }
    }
}

// ---------------------------------------------------------------------------
// Kernel C: per-graph softmax-attention pooling + BN(eval) + linear + lsm.
// ---------------------------------------------------------------------------
__global__ __launch_bounds__(256) void pool_final(
    const unsigned short* __restrict__ h, const float* __restrict__ gate,
    const int* __restrict__ batch,
    const float* __restrict__ gamma_, const float* __restrict__ beta_,
    const float* __restrict__ mean_, const float* __restrict__ var_,
    const float* __restrict__ Wl, const float* __restrict__ bl,
    float* __restrict__ out, int N)
{
    int g = blockIdx.x;
    int tid = threadIdx.x;

    int lo = 0, hi = N;
    while (lo < hi) { int mid = (lo + hi) >> 1; if (batch[mid] < g) lo = mid + 1; else hi = mid; }
    int start = lo;
    hi = N;
    while (lo < hi) { int mid = (lo + hi) >> 1; if (batch[mid] < g + 1) lo = mid + 1; else hi = mid; }
    int end = lo;

    __shared__ float red[4];
    __shared__ float pool_s[4 * 64];

    int lane = tid & 63;
    int wave = tid >> 6;

    float m = -FLT_MAX;
    for (int i = start + tid; i < end; i += 256) m = fmaxf(m, gate[i]);
    #pragma unroll
    for (int off = 32; off; off >>= 1) m = fmaxf(m, __shfl_xor(m, off));
    if (lane == 0) red[wave] = m;
    __syncthreads();
    m = fmaxf(fmaxf(red[0], red[1]), fmaxf(red[2], red[3]));
    __syncthreads();

    float s = 0.f;
    for (int i = start + tid; i < end; i += 256) s += expf(gate[i] - m);
    #pragma unroll
    for (int off = 32; off; off >>= 1) s += __shfl_xor(s, off);
    if (lane == 0) red[wave] = s;
    __syncthreads();
    s = red[0] + red[1] + red[2] + red[3];

    float a0 = 0.f, a1 = 0.f, a2 = 0.f, a3 = 0.f;
    int i = start + wave;
    for (; i + 12 < end; i += 16) {
        float e0 = expf(gate[i]      - m);
        float e1 = expf(gate[i + 4]  - m);
        float e2 = expf(gate[i + 8]  - m);
        float e3 = expf(gate[i + 12] - m);
        float t0 = bf2f(h[(size_t)(i)      * 64 + lane]);
        float t1 = bf2f(h[(size_t)(i + 4)  * 64 + lane]);
        float t2 = bf2f(h[(size_t)(i + 8)  * 64 + lane]);
        float t3 = bf2f(h[(size_t)(i + 12) * 64 + lane]);
        a0 = fmaf(e0, t0, a0);
        a1 = fmaf(e1, t1, a1);
        a2 = fmaf(e2, t2, a2);
        a3 = fmaf(e3, t3, a3);
    }
    for (; i < end; i += 4) {
        float e = expf(gate[i] - m);
        a0 = fmaf(e, bf2f(h[(size_t)i * 64 + lane]), a0);
    }
    pool_s[wave * 64 + lane] = (a0 + a1) + (a2 + a3);
    __syncthreads();

    if (wave == 0) {
        float p = pool_s[lane] + pool_s[64 + lane] + pool_s[128 + lane] + pool_s[192 + lane];
        p = (end > start) ? (p / s) : 0.f;
        float nrm = (p - mean_[lane]) / sqrtf(var_[lane] + BN_EPS) * gamma_[lane] + beta_[lane];
        float l0 = nrm * Wl[lane * 2 + 0];
        float l1 = nrm * Wl[lane * 2 + 1];
        #pragma unroll
        for (int off = 32; off; off >>= 1) {
            l0 += __shfl_xor(l0, off);
            l1 += __shfl_xor(l1, off);
        }
        if (lane == 0) {
            l0 += bl[0];
            l1 += bl[1];
            float mx = fmaxf(l0, l1);
            float lse = mx + logf(expf(l0 - mx) + expf(l1 - mx));
            out[g * 2 + 0] = l0 - lse;
            out[g * 2 + 1] = l1 - lse;
        }
    }
}

// ---------------------------------------------------------------------------
extern "C" void kernel_launch(void* const* d_in, const int* in_sizes, int n_in,
                              void* d_out, int out_size, void* d_ws, size_t ws_size,
                              hipStream_t stream)
{
    const float* x     = (const float*)d_in[0];
    const int*   eidx  = (const int*)d_in[1];   // [2, E]: row0=src, row1=dst
    const int*   batch = (const int*)d_in[2];
    const float* W1    = (const float*)d_in[3];
    const float* b1    = (const float*)d_in[4];
    const float* W2    = (const float*)d_in[5];
    const float* b2    = (const float*)d_in[6];
    const float* Wg    = (const float*)d_in[7];
    const float* bg    = (const float*)d_in[8];
    const float* bng   = (const float*)d_in[9];
    const float* bnb   = (const float*)d_in[10];
    const float* bnm   = (const float*)d_in[11];
    const float* bnv   = (const float*)d_in[12];
    const float* Wl    = (const float*)d_in[13];
    const float* bl    = (const float*)d_in[14];
    float* out = (float*)d_out;

    int N = in_sizes[0] / 64;        // requires N < 131072 (17-bit src pack)
    int E = in_sizes[1] / 2;
    int G = out_size / 2;
    int NP = ((N + 63) / 64) * 64;
    int NBUCK = (N + 127) / 128;     // <= NBUCKP
    int EB = (E + PBLK - 1) / PBLK;
    int GRID_A = 1024 > EB ? 1024 : EB;

    char* w = (char*)d_ws;
    int* packed2 = (int*)w;                     w += (size_t)NBUCK * ACAP * 4;
    unsigned short* hxb  = (unsigned short*)w;  w += (size_t)NP * 64 * 2;   // xb
    float* gate  = (float*)w;                   w += ((size_t)N * 4 + 255) / 256 * 256;
    int* bcur0   = (int*)w;                     w += NBUCKP * 4;
    unsigned short* w1t = (unsigned short*)w;   w += 4096 * 2;
    unsigned short* w2t = (unsigned short*)w;   w += 4096 * 2;
    unsigned short* hbuf = (unsigned short*)w;  // N*64 bf16 (dedicated h)

    const int* src = eidx;
    const int* dst = eidx + E;

    hipMemsetAsync(bcur0, 0, NBUCKP * sizeof(int), stream);

    prep_partition<<<GRID_A, 512, 0, stream>>>(x, hxb, W1, W2, w1t, w2t,
                                               src, dst, bcur0, packed2,
                                               N, E, EB);

    bucket_fused  <<<NBUCK, 512, 0, stream>>>(hxb, packed2, bcur0, w1t, w2t,
                                              b1, b2, Wg, bg, hbuf, gate, N);

    pool_final    <<<G, 256, 0, stream>>>(hbuf, gate, batch, bng, bnb, bnm, bnv,
                                          Wl, bl, out, N);
}